// Round 6
// baseline (308.191 us; speedup 1.0000x reference)
//
#include <hip/hip_runtime.h>
#include <math.h>

// QuantumNeuralNetwork: 12-qubit, 16-layer RY+CNOT-ring state-vector sim.
// Round 15: STRUCTURAL REWRITE - one wave per state, ZERO barriers.
//   64 threads/block (1 wave), 64 amps/lane as v2f (128 VGPRs state).
//   Frame: amp y = (m(t)<<6) | i,  m(t) = t ^ 3*t2 (6-bit involution).
//   Per layer, ALL 12 gates execute in-frame:
//     reg gates  (logical bits 0..5 = reg bits, qubits 11..6): reg-pair
//       masks 1,2,4,8,16,32 -> pk_fma shears (tan-factored, C deferred
//       globally as in r14).
//     lane gates (logical bits 6..11 = lane bits via m):
//       q5: bit6,  lane xor1  -> v_fmac_f32_dpp quad_perm[1,0,3,2], sg t0^t2
//       q4: bit7,  lane xor2  -> dpp quad_perm[2,3,0,1],            sg t1^t2
//       q3: bit8,  lane xor7  -> dpp row_half_mirror,               sg t2
//       q2: bit9,  lane xor8  -> dpp row_ror:8,                     sg t3
//       q1: bit10, lane xor16 -> ds_swizzle 0x401F + pk_fma,        sg t4
//       q0: bit11, lane xor32 -> ds_bpermute (t^32) + pk_fma,       sg t5
//   CNOT-ring perm G(y)=y^(y>>1)^(y0?0xC00:0) absorbed into ONE LDS trip
//   per layer: write slot (i<<6)|t (lane-contiguous), read slot(S(p)) with
//   S = Phi^-1 G Phi:  reg' = (i^(i>>1)) ^ (n0<<5),
//                      lane' = m(nn) ^ (i0*0x30),  n=m(t), nn=n^(n>>1).
//   Read addr = rb[n0^i5][i0] + ((i^(i>>1))&31)<<6  (4 per-thread bases,
//   disjoint bit fields -> additive immediates). Spot-checked: (t=5,i=3)->
//   slot 182, (t=1,i=0)->2049, (t=0,i=1)->112 vs direct G∘Phi. ✓
//   Single wave => in-order DS pipe self-synchronizes W->R: NO __syncthreads
//   anywhere. Measurement bits 11..7 = lane functionals (t5,t4,t3,t2,t1^t2):
//   shuffle-only reduction, no LDS.
// Numerics identical to r14 (tan shears + global (prod C)^2) -> same absmax.

#define DIM     4096
#define NLAYERS 16
#define BATCH   2048
#define NCLASS  5

typedef float v2f __attribute__((ext_vector_type(2)));

// lane map m: 6-bit involution, flips t0,t1 when t2 set
__device__ __forceinline__ int mmap(int x) { return x ^ (3 * ((x >> 2) & 1)); }

// ds_swizzle lane-xor16 (BitMode: xor=16, and=0x1F): 0x401F
template<int PAT>
__device__ __forceinline__ float swzf(float x) {
  return __int_as_float(__builtin_amdgcn_ds_swizzle(__float_as_int(x), PAT));
}

#define FOR64(M) M(0) M(1) M(2) M(3) M(4) M(5) M(6) M(7) M(8) M(9) \
 M(10) M(11) M(12) M(13) M(14) M(15) M(16) M(17) M(18) M(19) \
 M(20) M(21) M(22) M(23) M(24) M(25) M(26) M(27) M(28) M(29) \
 M(30) M(31) M(32) M(33) M(34) M(35) M(36) M(37) M(38) M(39) \
 M(40) M(41) M(42) M(43) M(44) M(45) M(46) M(47) M(48) M(49) \
 M(50) M(51) M(52) M(53) M(54) M(55) M(56) M(57) M(58) M(59) \
 M(60) M(61) M(62) M(63)

// reg-gate pair lists: (a, a|mask), a has the bit clear
#define PR1(M) M(0,1) M(2,3) M(4,5) M(6,7) M(8,9) M(10,11) M(12,13) M(14,15) \
 M(16,17) M(18,19) M(20,21) M(22,23) M(24,25) M(26,27) M(28,29) M(30,31) \
 M(32,33) M(34,35) M(36,37) M(38,39) M(40,41) M(42,43) M(44,45) M(46,47) \
 M(48,49) M(50,51) M(52,53) M(54,55) M(56,57) M(58,59) M(60,61) M(62,63)
#define PR2(M) M(0,2) M(1,3) M(4,6) M(5,7) M(8,10) M(9,11) M(12,14) M(13,15) \
 M(16,18) M(17,19) M(20,22) M(21,23) M(24,26) M(25,27) M(28,30) M(29,31) \
 M(32,34) M(33,35) M(36,38) M(37,39) M(40,42) M(41,43) M(44,46) M(45,47) \
 M(48,50) M(49,51) M(52,54) M(53,55) M(56,58) M(57,59) M(60,62) M(61,63)
#define PR4(M) M(0,4) M(1,5) M(2,6) M(3,7) M(8,12) M(9,13) M(10,14) M(11,15) \
 M(16,20) M(17,21) M(18,22) M(19,23) M(24,28) M(25,29) M(26,30) M(27,31) \
 M(32,36) M(33,37) M(34,38) M(35,39) M(40,44) M(41,45) M(42,46) M(43,47) \
 M(48,52) M(49,53) M(50,54) M(51,55) M(56,60) M(57,61) M(58,62) M(59,63)
#define PR8(M) M(0,8) M(1,9) M(2,10) M(3,11) M(4,12) M(5,13) M(6,14) M(7,15) \
 M(16,24) M(17,25) M(18,26) M(19,27) M(20,28) M(21,29) M(22,30) M(23,31) \
 M(32,40) M(33,41) M(34,42) M(35,43) M(36,44) M(37,45) M(38,46) M(39,47) \
 M(48,56) M(49,57) M(50,58) M(51,59) M(52,60) M(53,61) M(54,62) M(55,63)
#define PR16(M) M(0,16) M(1,17) M(2,18) M(3,19) M(4,20) M(5,21) M(6,22) M(7,23) \
 M(8,24) M(9,25) M(10,26) M(11,27) M(12,28) M(13,29) M(14,30) M(15,31) \
 M(32,48) M(33,49) M(34,50) M(35,51) M(36,52) M(37,53) M(38,54) M(39,55) \
 M(40,56) M(41,57) M(42,58) M(43,59) M(44,60) M(45,61) M(46,62) M(47,63)
#define PR32(M) M(0,32) M(1,33) M(2,34) M(3,35) M(4,36) M(5,37) M(6,38) M(7,39) \
 M(8,40) M(9,41) M(10,42) M(11,43) M(12,44) M(13,45) M(14,46) M(15,47) \
 M(16,48) M(17,49) M(18,50) M(19,51) M(20,52) M(21,53) M(22,54) M(23,55) \
 M(24,56) M(25,57) M(26,58) M(27,59) M(28,60) M(29,61) M(30,62) M(31,63)

// packed shear pair-rotation (kv, nkv in scope): lo -= k*hi; hi += k*lo_old
#define ROT(i, j) {                                          \
    const v2f ti = p##i, tj = p##j;                          \
    p##i = __builtin_elementwise_fma(nkv, tj, ti);           \
    p##j = __builtin_elementwise_fma(kv,  ti, tj); }

// broadcast k for (layer l, gate g): reg g&3 (literal), lane l+16*(g>>2)
#define GETK(g) \
  const float kG = __int_as_float(__builtin_amdgcn_readlane( \
      __float_as_int(vkg[(g) & 3]), l + (((g) >> 2) << 4)));

// fused DPP shear on 8 v2f (16 comps): p += sg * dpp_xor(p).
// s_nop 1 covers the VALU-write -> DPP-read hazard (distance -1/-2);
// within the block all 16 dst regs are distinct (no intra-block hazard).
#define DPP8(CTRL, iA,iB,iC,iD,iE,iF,iG,iH) { \
    float a0 = p##iA.x, a1 = p##iA.y, a2 = p##iB.x, a3 = p##iB.y, \
          a4 = p##iC.x, a5 = p##iC.y, a6 = p##iD.x, a7 = p##iD.y, \
          a8 = p##iE.x, a9 = p##iE.y, a10 = p##iF.x, a11 = p##iF.y, \
          a12 = p##iG.x, a13 = p##iG.y, a14 = p##iH.x, a15 = p##iH.y; \
    asm("s_nop 1\n\t" \
        "v_fmac_f32_dpp %0, %0, %16 " CTRL "\n\t" \
        "v_fmac_f32_dpp %1, %1, %16 " CTRL "\n\t" \
        "v_fmac_f32_dpp %2, %2, %16 " CTRL "\n\t" \
        "v_fmac_f32_dpp %3, %3, %16 " CTRL "\n\t" \
        "v_fmac_f32_dpp %4, %4, %16 " CTRL "\n\t" \
        "v_fmac_f32_dpp %5, %5, %16 " CTRL "\n\t" \
        "v_fmac_f32_dpp %6, %6, %16 " CTRL "\n\t" \
        "v_fmac_f32_dpp %7, %7, %16 " CTRL "\n\t" \
        "v_fmac_f32_dpp %8, %8, %16 " CTRL "\n\t" \
        "v_fmac_f32_dpp %9, %9, %16 " CTRL "\n\t" \
        "v_fmac_f32_dpp %10, %10, %16 " CTRL "\n\t" \
        "v_fmac_f32_dpp %11, %11, %16 " CTRL "\n\t" \
        "v_fmac_f32_dpp %12, %12, %16 " CTRL "\n\t" \
        "v_fmac_f32_dpp %13, %13, %16 " CTRL "\n\t" \
        "v_fmac_f32_dpp %14, %14, %16 " CTRL "\n\t" \
        "v_fmac_f32_dpp %15, %15, %16 " CTRL \
        : "+v"(a0), "+v"(a1), "+v"(a2), "+v"(a3), "+v"(a4), "+v"(a5), \
          "+v"(a6), "+v"(a7), "+v"(a8), "+v"(a9), "+v"(a10), "+v"(a11), \
          "+v"(a12), "+v"(a13), "+v"(a14), "+v"(a15) \
        : "v"(sg)); \
    p##iA.x = a0;  p##iA.y = a1;  p##iB.x = a2;  p##iB.y = a3; \
    p##iC.x = a4;  p##iC.y = a5;  p##iD.x = a6;  p##iD.y = a7; \
    p##iE.x = a8;  p##iE.y = a9;  p##iF.x = a10; p##iF.y = a11; \
    p##iG.x = a12; p##iG.y = a13; p##iH.x = a14; p##iH.y = a15; }

#define DPPGATE(CTRL) \
  DPP8(CTRL, 0,1,2,3,4,5,6,7) DPP8(CTRL, 8,9,10,11,12,13,14,15) \
  DPP8(CTRL, 16,17,18,19,20,21,22,23) DPP8(CTRL, 24,25,26,27,28,29,30,31) \
  DPP8(CTRL, 32,33,34,35,36,37,38,39) DPP8(CTRL, 40,41,42,43,44,45,46,47) \
  DPP8(CTRL, 48,49,50,51,52,53,54,55) DPP8(CTRL, 56,57,58,59,60,61,62,63)

__global__ __launch_bounds__(64)
void qnn_sim(const float* __restrict__ zr, const float* __restrict__ zi,
             const float* __restrict__ thetas, const int* __restrict__ y,
             float* __restrict__ out) {
  __shared__ v2f buf2[DIM];  // 32 KB trip buffer (one state)
  const int b = blockIdx.x;
  const int t = threadIdx.x;  // 0..63 (one wave)

  const int n  = mmap(t);              // m(t)
  const int n0 = n & 1;
  const int nn = n ^ (n >> 1);
  const int nnm = mmap(nn);            // lane' base of the trip read

  // 4 trip-read base slots (v2f units): rb[(n0^i5)][(i0)]
  const int rb00 = (n0 << 11) | nnm;
  const int rb10 = (n0 << 11) | (nnm ^ 0x30);
  const int rb01 = ((n0 ^ 1) << 11) | nnm;
  const int rb11 = ((n0 ^ 1) << 11) | (nnm ^ 0x30);

  const int bpaddr = (t ^ 32) << 2;    // ds_bpermute byte addr (lane xor32)

  // lane-gate sign bits (amp bit value at this lane)
  const bool s5 = ((t ^ (t >> 2)) & 1) != 0;          // bit6  = t0^t2
  const bool s4 = (((t >> 1) ^ (t >> 2)) & 1) != 0;   // bit7  = t1^t2
  const bool s3 = ((t >> 2) & 1) != 0;                // bit8  = t2
  const bool s2 = ((t >> 3) & 1) != 0;                // bit9  = t3
  const bool s1 = ((t >> 4) & 1) != 0;                // bit10 = t4
  const bool s0 = ((t >> 5) & 1) != 0;                // bit11 = t5

  v2f p0,p1,p2,p3,p4,p5,p6,p7,p8,p9,p10,p11,p12,p13,p14,p15,
      p16,p17,p18,p19,p20,p21,p22,p23,p24,p25,p26,p27,p28,p29,p30,p31,
      p32,p33,p34,p35,p36,p37,p38,p39,p40,p41,p42,p43,p44,p45,p46,p47,
      p48,p49,p50,p51,p52,p53,p54,p55,p56,p57,p58,p59,p60,p61,p62,p63;

  // ---- load: reg i holds amp y = (m(t)<<6) | i ----
  {
    const float4* zr4 = (const float4*)(zr + (size_t)b * DIM + (n << 6));
    const float4* zi4 = (const float4*)(zi + (size_t)b * DIM + (n << 6));
#define LDJ(j,A,B,C,D) { const float4 a = zr4[j]; const float4 c = zi4[j]; \
    p##A = (v2f){a.x, c.x}; p##B = (v2f){a.y, c.y}; \
    p##C = (v2f){a.z, c.z}; p##D = (v2f){a.w, c.w}; }
    LDJ(0,0,1,2,3)     LDJ(1,4,5,6,7)     LDJ(2,8,9,10,11)   LDJ(3,12,13,14,15)
    LDJ(4,16,17,18,19) LDJ(5,20,21,22,23) LDJ(6,24,25,26,27) LDJ(7,28,29,30,31)
    LDJ(8,32,33,34,35) LDJ(9,36,37,38,39) LDJ(10,40,41,42,43) LDJ(11,44,45,46,47)
    LDJ(12,48,49,50,51) LDJ(13,52,53,54,55) LDJ(14,56,57,58,59) LDJ(15,60,61,62,63)
#undef LDJ
  }

  // ---- per-wave trig table (4 VGPRs):
  // lanes 0..47:  vkg[j] = tan(theta[lane&15][4*(lane>>4)+j] / 2)
  // lanes 48..63: vkg[0] = C_l = prod cos(th/2), layer = lane-48
  float vkg[4];
  {
    if (t < 48) {
      const int lsrc = t & 15;
      const int gb = (t >> 4) << 2;
#pragma unroll
      for (int j = 0; j < 4; ++j) {
        const float a = 0.5f * thetas[lsrc * 12 + gb + j];
        vkg[j] = sinf(a) / cosf(a);
      }
    } else {
      const int lsrc = t - 48;
      float c = 1.f;
      for (int g = 0; g < 12; ++g) c *= cosf(0.5f * thetas[lsrc * 12 + g]);
      vkg[0] = c; vkg[1] = 0.f; vkg[2] = 0.f; vkg[3] = 0.f;
    }
  }
  // global deferred scale (prod_l C_l)^2
  float pcl = 1.f;
#pragma unroll
  for (int l2 = 0; l2 < NLAYERS; ++l2)
    pcl *= __int_as_float(__builtin_amdgcn_readlane(
        __float_as_int(vkg[0]), 48 + l2));
  const float pc2 = pcl * pcl;

#pragma unroll 1
  for (int l = 0; l < NLAYERS; ++l) {
    // ---- DPP lane gates: q5(xor1), q4(xor2), q3(xor7), q2(xor8) ----
    { GETK(5) const float sg = s5 ? kG : -kG;
      DPPGATE("quad_perm:[1,0,3,2] row_mask:0xf bank_mask:0xf") }
    { GETK(4) const float sg = s4 ? kG : -kG;
      DPPGATE("quad_perm:[2,3,0,1] row_mask:0xf bank_mask:0xf") }
    { GETK(3) const float sg = s3 ? kG : -kG;
      DPPGATE("row_half_mirror row_mask:0xf bank_mask:0xf") }
    { GETK(2) const float sg = s2 ? kG : -kG;
      DPPGATE("row_ror:8 row_mask:0xf bank_mask:0xf") }

    // ---- swizzle gate q1 (lane xor16) ----
    {
      GETK(1)
      const float sg = s1 ? kG : -kG;
      const v2f skv = {sg, sg};
#define SWG(i) { v2f pr; pr.x = swzf<0x401F>(p##i.x); pr.y = swzf<0x401F>(p##i.y); \
      p##i = __builtin_elementwise_fma(skv, pr, p##i); }
      FOR64(SWG)
#undef SWG
    }

    // ---- bpermute gate q0 (lane xor32) ----
    {
      GETK(0)
      const float sg = s0 ? kG : -kG;
      const v2f skv = {sg, sg};
#define BPG(i) { v2f pr; \
      pr.x = __int_as_float(__builtin_amdgcn_ds_bpermute(bpaddr, __float_as_int(p##i.x))); \
      pr.y = __int_as_float(__builtin_amdgcn_ds_bpermute(bpaddr, __float_as_int(p##i.y))); \
      p##i = __builtin_elementwise_fma(skv, pr, p##i); }
      FOR64(BPG)
#undef BPG
    }

    // ---- reg gates q11..q6 (reg-bit masks 1,2,4,8,16,32) ----
    { GETK(11) const v2f kv = {kG,kG}, nkv = {-kG,-kG}; PR1(ROT) }
    { GETK(10) const v2f kv = {kG,kG}, nkv = {-kG,-kG}; PR2(ROT) }
    { GETK(9)  const v2f kv = {kG,kG}, nkv = {-kG,-kG}; PR4(ROT) }
    { GETK(8)  const v2f kv = {kG,kG}, nkv = {-kG,-kG}; PR8(ROT) }
    { GETK(7)  const v2f kv = {kG,kG}, nkv = {-kG,-kG}; PR16(ROT) }
    { GETK(6)  const v2f kv = {kG,kG}, nkv = {-kG,-kG}; PR32(ROT) }

    // ---- trip: CNOT-ring perm (G absorbed), single wave => no barrier.
    // W: slot (i<<6)|t (lane-contiguous); in-order DS pipe orders W before R.
#define TW(i) buf2[((i) << 6) + t] = p##i;
    FOR64(TW)
#undef TW
    asm volatile("" ::: "memory");  // compile-time fence: keep W before R
#define TR(i) p##i = buf2[(((i) & 1) ? (((i) & 32) ? rb11 : rb10) \
                                     : (((i) & 32) ? rb01 : rb00)) \
                          + (((((i) ^ ((i) >> 1)) & 31)) << 6)];
    FOR64(TR)
#undef TR
  }

  // ---- Z expectations: wire w sign = amp bit (11-w) ----
  // bit11=t5, bit10=t4, bit9=t3, bit8=t2, bit7=t1^t2 (all lane-uniform)
  float P = 0.f;
#define ACC(i) P = __builtin_fmaf(p##i.x, p##i.x, P); \
               P = __builtin_fmaf(p##i.y, p##i.y, P);
  FOR64(ACC)
#undef ACC
  P *= pc2;
  float e0 = s0 ? -P : P;                        // t5
  float e1 = s1 ? -P : P;                        // t4
  float e2 = s2 ? -P : P;                        // t3
  float e3 = s3 ? -P : P;                        // t2
  float e4 = s4 ? -P : P;                        // t1^t2
#pragma unroll
  for (int off = 32; off >= 1; off >>= 1) {
    e0 += __shfl_xor(e0, off);
    e1 += __shfl_xor(e1, off);
    e2 += __shfl_xor(e2, off);
    e3 += __shfl_xor(e3, off);
    e4 += __shfl_xor(e4, off);
  }
  if (t == 0) {
    float* op = out + 1 + (size_t)b * NCLASS;
    op[0] = e0; op[1] = e1; op[2] = e2; op[3] = e3; op[4] = e4;
    // fused NLL: loss contribution = (logsumexp(o) - o[y]) / BATCH
    const float m = fmaxf(fmaxf(fmaxf(e0, e1), fmaxf(e2, e3)), e4);
    const float sum = expf(e0 - m) + expf(e1 - m) + expf(e2 - m) +
                      expf(e3 - m) + expf(e4 - m);
    const int yb = y[b];
    const float oy = (yb == 0) ? e0 : (yb == 1) ? e1 : (yb == 2) ? e2
                   : (yb == 3) ? e3 : e4;
    const float nll = (m + logf(sum)) - oy;
    atomicAdd(out, nll * (1.0f / BATCH));
  }
}

extern "C" void kernel_launch(void* const* d_in, const int* in_sizes, int n_in,
                              void* d_out, int out_size, void* d_ws, size_t ws_size,
                              hipStream_t stream) {
  const float* zr = (const float*)d_in[0];
  const float* zi = (const float*)d_in[1];
  const float* th = (const float*)d_in[2];
  const int*   y  = (const int*)d_in[3];
  float* out = (float*)d_out;
  hipMemsetAsync(out, 0, sizeof(float), stream);  // zero loss accumulator
  qnn_sim<<<BATCH, 64, 0, stream>>>(zr, zi, th, y, out);
}